// Round 13
// baseline (100.289 us; speedup 1.0000x reference)
//
#include <hip/hip_runtime.h>
#include <stdint.h>

#define DIM     128
#define NMEM    16384
#define NQ_TOT  2048
#define TQ      128                   // queries per WG (2 q-tiles per wave)
#define TN      32                    // mem rows per iter (8KB F + 8KB T tiles)
#define NTILES_TOT (NMEM / TN)        // 512
#define QROWS   (NQ_TOT / TQ)         // 16
#define SHIFT   30.0f

typedef short    s8v __attribute__((ext_vector_type(8)));
typedef _Float16 h8v __attribute__((ext_vector_type(8)));
typedef float    f4v __attribute__((ext_vector_type(4)));

// ---- workspace layout (bytes) ----
#define OFF_MF16  0u
#define OFF_MHIT  (4u << 20)
#define OFF_NUM   (8u << 20)
#define NUM_BYTES(c)  ((uint32_t)(c) * NQ_TOT * DIM * 2u)   // bf16 partials
#define OFF_DEN(c)    (OFF_NUM + NUM_BYTES(c))
#define WS_NEED(c)    ((size_t)(OFF_DEN(c) + (uint32_t)(c) * NQ_TOT * 4u))

__device__ __forceinline__ uint16_t f2bf(float x) {
    uint32_t u = __float_as_uint(x);
    uint32_t r = u + 0x7fffu + ((u >> 16) & 1u);   // RNE
    return (uint16_t)(r >> 16);
}
__device__ __forceinline__ float bf2f(uint16_t h) {
    return __uint_as_float(((uint32_t)h) << 16);
}
__device__ __forceinline__ uint16_t f2h(float x) {  // fp16 RNE via v_cvt_f16_f32
    union { _Float16 h; uint16_t u; } c;
    c.h = (_Float16)x;
    return c.u;
}

// ==== pre-pass: fp32 memory -> fp16 M (row-major) + bf16 M^T ====
__global__ __launch_bounds__(256)
void convert_kernel(const float* __restrict__ mem, uint16_t* __restrict__ mf16,
                    uint16_t* __restrict__ mhit) {
    __shared__ uint16_t T[DIM * 65];           // [d][n], stride 65 breaks bank conflict
    const int b  = blockIdx.x;                 // 256 blocks x 64 rows
    const int t  = threadIdx.x;
    const int n0 = b * 64;
    #pragma unroll
    for (int k = 0; k < 8; ++k) {
        const int idx4 = t + k * 256;
        const int r    = idx4 >> 5;
        const int c4   = idx4 & 31;
        const float4 v = ((const float4*)(mem + (size_t)(n0 + r) * DIM))[c4];
        *(ushort4*)&mf16[(size_t)(n0 + r) * DIM + c4 * 4] =
            make_ushort4(f2h(v.x), f2h(v.y), f2h(v.z), f2h(v.w));
        T[(c4 * 4 + 0) * 65 + r] = f2bf(v.x);
        T[(c4 * 4 + 1) * 65 + r] = f2bf(v.y);
        T[(c4 * 4 + 2) * 65 + r] = f2bf(v.z);
        T[(c4 * 4 + 3) * 65 + r] = f2bf(v.w);
    }
    __syncthreads();
    #pragma unroll
    for (int p = 0; p < 4; ++p) {
        const int d    = (t >> 3) + p * 32;
        const int part = t & 7;
        uint16_t tmp[8];
        #pragma unroll
        for (int e = 0; e < 8; ++e) tmp[e] = T[d * 65 + part * 8 + e];
        *(uint4*)&mhit[(size_t)d * NMEM + n0 + part * 8] = *(const uint4*)tmp;
    }
}

// ==== main attention: TN=32, 2-DEEP PREFETCH (triple-buffer), reg repack =====
// R21: attn has been invariant ~40us across sync/occupancy/LDS/repack changes
// (R11..R20) — all body-side levers. Remaining shared structure: staging has
// only ONE body of latency overlap (issue t+1, compute t, drain-all). L2/L3
// round-trip + 64KB/CU delivery ≈ 2400-3000cyc > body ≈ 1500cyc -> every
// iter pays the uncovered staging shadow. Fix: prefetch TWO tiles ahead.
//   - TN=32 tiles (8KB F + 8KB T), THREE buffers = 49,152 B LDS (no Ps —
//     R20's in-register permlane repack, proven).
//   - top of iter: s_waitcnt vmcnt(4) lgkmcnt(0) (oldest tile's own 4 loads
//     done; newest 4 stay in flight) + barrier; then STAGE(t+2) into the
//     buffer freed by t-1 (reads completed: every wave drained lgkm before
//     its barrier arrival). Staging latency spans TWO bodies -> hidden.
//   - clamp-staging in the last 2 iters keeps vmcnt counts uniform; the
//     final __syncthreads() drains the tail before SM reuse.
// All compute formulas hardware-proven: TN=32 staging/QK/PV-bt (R18), ksP=0
// register repack (R20), q-split PV + epilogue (R18/R20).
template <int NCHK>
__global__ __launch_bounds__(256, 2)
void attn_kernel(const float* __restrict__ query,
                 const uint16_t* __restrict__ mf16,
                 const uint16_t* __restrict__ mhit,
                 uint16_t* __restrict__ num, float* __restrict__ den) {
    // shorts: F0|F1|F2 @0,4096,8192 | T0|T1|T2 @12288,16384,20480 -> 49,152 B
    __shared__ __align__(16) uint16_t SM[24576];

    const int tid   = threadIdx.x;
    const int wv    = tid >> 6;
    const int lane  = tid & 63;
    const int l16   = lane & 15;
    const int quad  = lane >> 4;
    const int bx    = blockIdx.x;
    constexpr int CPX = NCHK / 8;              // chunks pinned per XCD
    const int xcd   = bx & 7;
    const int j     = bx >> 3;
    const int chunk = xcd * CPX + (j % CPX);
    const int qrow  = j / CPX;                 // 0..QROWS-1
    const int q0    = qrow * TQ;
    constexpr int ITERS = NTILES_TOT / NCHK;   // 16 @ NCHK=32
    const int nbase = chunk * (NMEM / NCHK);

    // ---- staging: 16 x 16B global_load_lds per tile, 4 per wave ----
    // F tile: 32 n-rows x 128 d fp16 (ids 0-7); T tile: 128 d x 32 n bf16
    // (ids 8-15). Waves 0,1 -> F; waves 2,3 -> T. (R18-proven formulas.)
    auto STAGE = [&](int nb, int buf) {
        #pragma unroll
        for (int ii = 0; ii < 4; ++ii) {
            const int id = wv * 4 + ii;
            if (id < 8) {                      // F granule-set
                const int s = id * 64 + lane;  // 0..511
                const int r = s >> 4, c = (s & 15) ^ (r & 7);
                const uint16_t* g = mf16 + (size_t)(nb + r) * DIM + c * 8;
                __builtin_amdgcn_global_load_lds(
                    (const __attribute__((address_space(1))) void*)g,
                    (__attribute__((address_space(3))) void*)&SM[buf * 4096 + id * 512], 16, 0, 0);
            } else {                           // T granule-set
                const int jj = id - 8;
                const int s = jj * 64 + lane;  // 0..511
                const int d = s >> 2, c = (s & 3) ^ (d & 3);
                const uint16_t* g = mhit + (size_t)d * NMEM + nb + c * 8;
                __builtin_amdgcn_global_load_lds(
                    (const __attribute__((address_space(1))) void*)g,
                    (__attribute__((address_space(3))) void*)&SM[12288 + buf * 4096 + jj * 512], 16, 0, 0);
            }
        }
    };
    STAGE(nbase, 0);                           // prologue: tiles 0,1 in flight
    STAGE(nbase + TN, 1);

    // ---- Q fragments: 2 q-tiles x 4 k-chunks (fp16), q on l16 ----
    h8v qf[2][4];
    #pragma unroll
    for (int qt = 0; qt < 2; ++qt) {
        const float* qp = query + (size_t)(q0 + wv * 32 + qt * 16 + l16) * DIM + quad * 8;
        #pragma unroll
        for (int ks = 0; ks < 4; ++ks) {
            const float4 a = *(const float4*)(qp + ks * 32);
            const float4 b = *(const float4*)(qp + ks * 32 + 4);
            h8v vh;
            vh[0] = (_Float16)a.x; vh[1] = (_Float16)a.y;
            vh[2] = (_Float16)a.z; vh[3] = (_Float16)a.w;
            vh[4] = (_Float16)b.x; vh[5] = (_Float16)b.y;
            vh[6] = (_Float16)b.z; vh[7] = (_Float16)b.w;
            qf[qt][ks] = vh;
        }
    }

    f4v oacc[2][8];                            // O[q = wv*32+qt*16+quad*4+rg][d = dt*16+l16]
    float dacc[2] = {0.f, 0.f};
    #pragma unroll
    for (int qt = 0; qt < 2; ++qt)
        #pragma unroll
        for (int dt = 0; dt < 8; ++dt)
            oacc[qt][dt] = (f4v){0.f, 0.f, 0.f, 0.f};

    for (int it = 0; it < ITERS; ++it) {
        const int cur  = it % 3;
        const int nbuf = (it + 2) % 3;         // buffer of tile it-1 (freed)
        const int nnx  = (it + 2 < ITERS) ? nbase + (it + 2) * TN : nbase;  // clamp

        // oldest tile's own 4 loads landed (4 newest stay in flight);
        // lgkmcnt(0): own ds_reads of tile it-1 done before its buffer is
        // DMA-overwritten post-barrier. Barrier: cross-wave tile-it visibility.
        asm volatile("s_waitcnt vmcnt(4) lgkmcnt(0)" ::: "memory");
        __builtin_amdgcn_s_barrier();
        __builtin_amdgcn_sched_barrier(0);

        STAGE(nnx, nbuf);                      // tile it+2: 2 bodies of cover

        // ---- QK^T swapped: sacc = S^T, q on l16; 2 n-subtiles (R18) ----
        const uint16_t* F = SM + cur * 4096;
        f4v sacc[2][2];
        #pragma unroll
        for (int qt = 0; qt < 2; ++qt)
            #pragma unroll
            for (int nt = 0; nt < 2; ++nt)
                sacc[qt][nt] = (f4v){0.f, 0.f, 0.f, 0.f};
        #pragma unroll
        for (int nt = 0; nt < 2; ++nt) {
            const int r   = nt * 16 + l16;     // A-row = mem row (lane l16)
            const int rsw = r & 7;
            #pragma unroll
            for (int ks = 0; ks < 4; ++ks) {
                const int c = ks * 4 + quad;
                const h8v bm = *(const h8v*)&F[r * DIM + ((c ^ rsw) << 3)];
                #pragma unroll
                for (int qt = 0; qt < 2; ++qt)
                    sacc[qt][nt] = __builtin_amdgcn_mfma_f32_16x16x32_f16(bm, qf[qt][ks], sacc[qt][nt], 0, 0, 0);
            }
        }

        // ---- exp + f2bf pack (proven); den from rounded vals ----
        uint32_t W[2][2][2];
        #pragma unroll
        for (int qt = 0; qt < 2; ++qt)
            #pragma unroll
            for (int nt = 0; nt < 2; ++nt) {
                const uint16_t pb0 = f2bf(__expf(sacc[qt][nt][0] - SHIFT));
                const uint16_t pb1 = f2bf(__expf(sacc[qt][nt][1] - SHIFT));
                const uint16_t pb2 = f2bf(__expf(sacc[qt][nt][2] - SHIFT));
                const uint16_t pb3 = f2bf(__expf(sacc[qt][nt][3] - SHIFT));
                dacc[qt] += (bf2f(pb0) + bf2f(pb1)) + (bf2f(pb2) + bf2f(pb3));
                W[qt][nt][0] = (uint32_t)pb0 | ((uint32_t)pb1 << 16);
                W[qt][nt][1] = (uint32_t)pb2 | ((uint32_t)pb3 << 16);
            }

        // ---- in-register repack (R20-proven, ksP=0 collapse): ----
        // pa[qt] lane (l16,quad) = P[q][n = 8quad + j], n in 0..31
        s8v pa[2];
        #pragma unroll
        for (int qt = 0; qt < 2; ++qt) {
            uint32_t a0 = W[qt][0][0];
            uint32_t a1 = W[qt][0][1];
            uint32_t b0 = W[qt][1][0];
            uint32_t b1 = W[qt][1][1];
            asm("v_permlane32_swap_b32 %0, %1" : "+v"(a0), "+v"(b0));
            asm("v_permlane32_swap_b32 %0, %1" : "+v"(a1), "+v"(b1));
            asm("v_permlane16_swap_b32 %0, %1" : "+v"(a0), "+v"(b0));
            asm("v_permlane16_swap_b32 %0, %1" : "+v"(a1), "+v"(b1));
            union { uint32_t d[4]; s8v v8; } P;
            P.d[0] = a0;                       // n = 8quad + {0,1}
            P.d[1] = a1;                       // n = 8quad + {2,3}
            P.d[2] = b0;                       // n = 8quad + {4,5}
            P.d[3] = b1;                       // n = 8quad + {6,7}
            pa[qt] = P.v8;
        }

        // ---- PV q-split (R18-proven): A = pa (reg), B = V^T from LDS; K=32 --
        const uint16_t* T = SM + 12288 + cur * 4096;
        #pragma unroll
        for (int dt = 0; dt < 8; ++dt) {
            const int d  = dt * 16 + l16;
            const s8v bt = *(const s8v*)&T[d * TN + ((quad ^ (d & 3)) << 3)];
            #pragma unroll
            for (int qt = 0; qt < 2; ++qt)
                oacc[qt][dt] = __builtin_amdgcn_mfma_f32_16x16x32_bf16(pa[qt], bt, oacc[qt][dt], 0, 0, 0);
        }
    }

    // ---- denominator: q = l16; sum the 4 quads' disjoint n-sets ----
    #pragma unroll
    for (int qt = 0; qt < 2; ++qt) {
        dacc[qt] += __shfl_xor(dacc[qt], 16, 64);
        dacc[qt] += __shfl_xor(dacc[qt], 32, 64);
    }
    __syncthreads();                           // drains tail DMA + LDS; SM reusable
    if (quad == 0) {
        #pragma unroll
        for (int qt = 0; qt < 2; ++qt)
            den[chunk * NQ_TOT + q0 + wv * 32 + qt * 16 + l16] = dacc[qt];
    }
    // ---- O merge into LDS (bf16) for coalesced stores (R18-proven) ----
    uint16_t* Obuf = SM;                       // 128 q x 128 d x 2B = 32 KB (fits 48K)
    #pragma unroll
    for (int qt = 0; qt < 2; ++qt)
        #pragma unroll
        for (int dt = 0; dt < 8; ++dt)
            #pragma unroll
            for (int rg = 0; rg < 4; ++rg) {
                const int qq = wv * 32 + qt * 16 + quad * 4 + rg;
                const int dd = dt * 16 + l16;
                Obuf[qq * DIM + dd] = f2bf(oacc[qt][dt][rg]);
            }
    __syncthreads();
    {
        uint4* dst = (uint4*)(num + ((size_t)chunk * NQ_TOT + q0) * DIM);
        const uint4* src = (const uint4*)Obuf;
        #pragma unroll
        for (int k = 0; k < 8; ++k) {
            const int f = tid + k * 256;       // 2048 uint4s (32 KB)
            dst[f] = src[f];
        }
    }
}

// ============ final reduce over chunks + normalize ============
template <int NCHK>
__global__ __launch_bounds__(256)
void reduce_kernel(const uint16_t* __restrict__ num, const float* __restrict__ den,
                   float* __restrict__ out) {
    const int f = blockIdx.x * 256 + threadIdx.x;   // 65536 groups of 4
    const int q = f >> 5;
    float4 ns = make_float4(0.f, 0.f, 0.f, 0.f);
    float ds = 0.f;
    #pragma unroll
    for (int c = 0; c < NCHK; ++c) {
        const ushort4 v = ((const ushort4*)num)[c * (NQ_TOT * DIM / 4) + f];
        ns.x += bf2f(v.x); ns.y += bf2f(v.y); ns.z += bf2f(v.z); ns.w += bf2f(v.w);
        ds += den[c * NQ_TOT + q];
    }
    const float inv = 1.0f / ds;
    ((float4*)out)[f] = make_float4(ns.x * inv, ns.y * inv, ns.z * inv, ns.w * inv);
}

// ============ fallback (round-1 fp32 kernel) if ws too small ============
#define FTQ 8
#define FTN 64
#define FNTILES (NMEM / FTN)
#define FBLOCK 512
#define MPAD 132
#define PPAD 68

__global__ __launch_bounds__(FBLOCK, 2)
void sparse_attn_fp32(const float* __restrict__ query,
                      const float* __restrict__ memory,
                      float* __restrict__ out) {
    __shared__ float Qs[FTQ * MPAD];
    __shared__ float Ms[FTN * MPAD];
    __shared__ float Psh[FTQ * PPAD];
    __shared__ float Rd[FTQ * PPAD];
    const int tid = threadIdx.x;
    const int q = tid & 7, rest = tid >> 3;
    const int ng = rest, dg = rest & 31, half = rest >> 5;
    const long q0 = (long)blockIdx.x * FTQ;
    if (tid < FTQ * DIM / 4) {
        const float4 v = ((const float4*)(query + q0 * DIM))[tid];
        *(float4*)&Qs[(tid >> 5) * MPAD + ((tid & 31) << 2)] = v;
    }
    float4 pf[4];
    {
        const float4* msrc = (const float4*)memory;
        #pragma unroll
        for (int k = 0; k < 4; ++k) pf[k] = msrc[tid + k * FBLOCK];
    }
    float4 acc = make_float4(0.f, 0.f, 0.f, 0.f);
    float l_part = 0.f;
    for (int t = 0; t < FNTILES; ++t) {
        __syncthreads();
        #pragma unroll
        for (int k = 0; k < 4; ++k) {
            const int f4 = tid + k * FBLOCK;
            *(float4*)&Ms[(f4 >> 5) * MPAD + ((f4 & 31) << 2)] = pf[k];
        }
        __syncthreads();
        if (t + 1 < FNTILES) {
            const float4* msrc = (const float4*)(memory + (long)(t + 1) * FTN * DIM);
            #pragma unroll
            for (int k = 0; k < 4; ++k) pf[k] = msrc[tid + k * FBLOCK];
        }
        float4 s4 = make_float4(0.f, 0.f, 0.f, 0.f);
        const float* qrow = &Qs[q * MPAD];
        const float* mrow = &Ms[ng * MPAD];
        #pragma unroll
        for (int jj = 0; jj < 32; ++jj) {
            const float4 qv = *(const float4*)&qrow[jj * 4];
            const float4 mv = *(const float4*)&mrow[jj * 4];
            s4.x += qv.x * mv.x; s4.y += qv.y * mv.y;
            s4.z += qv.z * mv.z; s4.w += qv.w * mv.w;
        }
        const float p = __expf(((s4.x + s4.y) + (s4.z + s4.w)) - SHIFT);
        Psh[q * PPAD + ng] = p;
        l_part += p;
        __syncthreads();
        #pragma unroll
        for (int n = 0; n < 32; ++n) {
            const int nn = half * 32 + n;
            const float pw = Psh[q * PPAD + nn];
            const float4 mv = *(const float4*)&Ms[nn * MPAD + dg * 4];
            acc.x += pw * mv.x; acc.y += pw * mv.y;
            acc.z += pw * mv.z; acc.w += pw * mv.w;
        }
    }
    __syncthreads();
    Rd[q * PPAD + rest] = l_part;
    if (half == 1) *(float4*)&Ms[q * MPAD + dg * 4] = acc;
    __syncthreads();
    if (half == 0) {
        const float4 o2 = *(const float4*)&Ms[q * MPAD + dg * 4];
        float l = 0.f;
        #pragma unroll 8
        for (int i = 0; i < 64; ++i) l += Rd[q * PPAD + i];
        const float inv = 1.0f / l;
        float4 o;
        o.x = (acc.x + o2.x) * inv; o.y = (acc.y + o2.y) * inv;
        o.z = (acc.z + o2.z) * inv; o.w = (acc.w + o2.w) * inv;
        *(float4*)(out + (q0 + q) * DIM + dg * 4) = o;
    }
}

extern "C" void kernel_launch(void* const* d_in, const int* in_sizes, int n_in,
                              void* d_out, int out_size, void* d_ws, size_t ws_size,
                              hipStream_t stream) {
    const float* query  = (const float*)d_in[0];
    const float* memory = (const float*)d_in[1];
    float* out = (float*)d_out;
    if (ws_size >= WS_NEED(16)) {
        uint16_t* mf16 = (uint16_t*)((char*)d_ws + OFF_MF16);
        uint16_t* mhit = (uint16_t*)((char*)d_ws + OFF_MHIT);
        uint16_t* num  = (uint16_t*)((char*)d_ws + OFF_NUM);
        convert_kernel<<<NMEM / 64, 256, 0, stream>>>(memory, mf16, mhit);
        if (ws_size >= WS_NEED(32)) {
            float* den = (float*)((char*)d_ws + OFF_DEN(32));
            attn_kernel<32><<<QROWS * 32, 256, 0, stream>>>(query, mf16, mhit, num, den);
            reduce_kernel<32><<<NQ_TOT * DIM / 4 / 256, 256, 0, stream>>>(num, den, out);
        } else {
            float* den = (float*)((char*)d_ws + OFF_DEN(16));
            attn_kernel<16><<<QROWS * 16, 256, 0, stream>>>(query, mf16, mhit, num, den);
            reduce_kernel<16><<<NQ_TOT * DIM / 4 / 256, 256, 0, stream>>>(num, den, out);
        }
    } else {
        sparse_attn_fp32<<<NQ_TOT / FTQ, FBLOCK, 0, stream>>>(query, memory, out);
    }
}

// Round 14
// 97.959 us; speedup vs baseline: 1.0238x; 1.0238x over previous
//
#include <hip/hip_runtime.h>
#include <stdint.h>

#define DIM     128
#define NMEM    16384
#define NQ_TOT  2048
#define TQ      128                   // queries per WG (q-split QK across waves)
#define TN      64                    // mem rows per iter
#define NTILES_TOT (NMEM / TN)        // 256
#define QROWS   (NQ_TOT / TQ)         // 16
#define SHIFT   30.0f
#define PSTR    88                    // Ps^T row stride (shorts): 176B ≡ 0 mod 16

typedef short    s8v __attribute__((ext_vector_type(8)));
typedef _Float16 h8v __attribute__((ext_vector_type(8)));
typedef float    f4v __attribute__((ext_vector_type(4)));

// ---- workspace layout (bytes) ----
#define OFF_MF16  0u
#define OFF_MHIT  (4u << 20)
#define OFF_NUM   (8u << 20)
#define NUM_BYTES(c)  ((uint32_t)(c) * NQ_TOT * DIM * 2u)   // bf16 partials
#define OFF_DEN(c)    (OFF_NUM + NUM_BYTES(c))
#define WS_NEED(c)    ((size_t)(OFF_DEN(c) + (uint32_t)(c) * NQ_TOT * 4u))

__device__ __forceinline__ uint16_t f2bf(float x) {
    uint32_t u = __float_as_uint(x);
    uint32_t r = u + 0x7fffu + ((u >> 16) & 1u);   // RNE
    return (uint16_t)(r >> 16);
}
__device__ __forceinline__ float bf2f(uint16_t h) {
    return __uint_as_float(((uint32_t)h) << 16);
}
__device__ __forceinline__ uint16_t f2h(float x) {  // fp16 RNE via v_cvt_f16_f32
    union { _Float16 h; uint16_t u; } c;
    c.h = (_Float16)x;
    return c.u;
}

// ==== pre-pass: fp32 memory -> fp16 M (row-major) + bf16 M^T ====
__global__ __launch_bounds__(256)
void convert_kernel(const float* __restrict__ mem, uint16_t* __restrict__ mf16,
                    uint16_t* __restrict__ mhit) {
    __shared__ uint16_t T[DIM * 65];           // [d][n], stride 65 breaks bank conflict
    const int b  = blockIdx.x;                 // 256 blocks x 64 rows
    const int t  = threadIdx.x;
    const int n0 = b * 64;
    #pragma unroll
    for (int k = 0; k < 8; ++k) {
        const int idx4 = t + k * 256;
        const int r    = idx4 >> 5;
        const int c4   = idx4 & 31;
        const float4 v = ((const float4*)(mem + (size_t)(n0 + r) * DIM))[c4];
        *(ushort4*)&mf16[(size_t)(n0 + r) * DIM + c4 * 4] =
            make_ushort4(f2h(v.x), f2h(v.y), f2h(v.z), f2h(v.w));
        T[(c4 * 4 + 0) * 65 + r] = f2bf(v.x);
        T[(c4 * 4 + 1) * 65 + r] = f2bf(v.y);
        T[(c4 * 4 + 2) * 65 + r] = f2bf(v.z);
        T[(c4 * 4 + 3) * 65 + r] = f2bf(v.w);
    }
    __syncthreads();
    #pragma unroll
    for (int p = 0; p < 4; ++p) {
        const int d    = (t >> 3) + p * 32;
        const int part = t & 7;
        uint16_t tmp[8];
        #pragma unroll
        for (int e = 0; e < 8; ++e) tmp[e] = T[d * 65 + part * 8 + e];
        *(uint4*)&mhit[(size_t)d * NMEM + n0 + part * 8] = *(const uint4*)tmp;
    }
}

// ==== main attention: TQ=128, swapped QK, Ps^T via LDS (vectorized) =========
// R22 = R15 verbatim — the session's best measured kernel (97.7 us).
// Structural levers tested and NEUTRAL on attn (R10/R11/R19/R20/R21):
// counted-vmcnt sync, occupancy 3/CU, q-split PV + 1 barrier/iter,
// in-register permlane repack (no Ps), 2-deep prefetch. attn is a
// latency/issue-structure floor (~40us, all pipes <25%); timed window is
// dominated by the harness fill (~43us) + attn + fixed ~15us.
//  - QK computes mfma(M,Q) -> S^T: q on l16, n on quad*4+rg.
//  - exp + f2bf packs 4 consecutive-n values into one uint2 -> ONE
//    ds_write_b64 per (qt,nt); Ps^T rows are [q][n] contiguous.
//  - PV: pf = Ps[q*PSTR + ksP*32 + quad*8] b128 reads (d-split, R10 form).
//  - den: per-lane (q=l16) partials; shfl over quads; direct global write.
template <int NCHK>
__global__ __launch_bounds__(256, 2)
void attn_kernel(const float* __restrict__ query,
                 const uint16_t* __restrict__ mf16,
                 const uint16_t* __restrict__ mhit,
                 uint16_t* __restrict__ num, float* __restrict__ den) {
    // carve: MsF16 8192 | MsT 8192 | Ps^T 128*88=11264 -> 27648 shorts (55296B)
    __shared__ __align__(16) uint16_t SM[27648];
    uint16_t* MsF16 = SM;                      // [n64][d-granule^swz] fp16
    uint16_t* MsT   = SM + 8192;               // [d128][n-granule^swz] bf16
    uint16_t* Ps    = SM + 16384;              // [q128][PSTR] bf16 (P^T: [q][n])

    const int tid   = threadIdx.x;
    const int wv    = tid >> 6;
    const int lane  = tid & 63;
    const int l16   = lane & 15;
    const int quad  = lane >> 4;
    const int bx    = blockIdx.x;
    constexpr int CPX = NCHK / 8;              // chunks pinned per XCD
    const int xcd   = bx & 7;
    const int j     = bx >> 3;
    const int chunk = xcd * CPX + (j % CPX);
    const int qrow  = j / CPX;                 // 0..QROWS-1
    const int q0    = qrow * TQ;
    constexpr int ITERS = NTILES_TOT / NCHK;
    const int nbase = chunk * (NMEM / NCHK);

    // ---- stage tile 0: each wave issues its 4 F then its 4 T loads ----
    #pragma unroll
    for (int ii = 0; ii < 4; ++ii) {
        const int fid = wv * 4 + ii;
        const int s = fid * 64 + lane;
        const int r = s >> 4, c = (s & 15) ^ (r & 7);
        const uint16_t* g = mf16 + (size_t)(nbase + r) * DIM + c * 8;
        __builtin_amdgcn_global_load_lds(
            (const __attribute__((address_space(1))) void*)g,
            (__attribute__((address_space(3))) void*)&MsF16[fid * 512], 16, 0, 0);
    }
    #pragma unroll
    for (int ii = 0; ii < 4; ++ii) {
        const int jj = wv * 4 + ii;
        const int s = jj * 64 + lane;
        const int d = s >> 3, c = (s & 7) ^ (d & 7);
        const uint16_t* g = mhit + (size_t)d * NMEM + nbase + c * 8;
        __builtin_amdgcn_global_load_lds(
            (const __attribute__((address_space(1))) void*)g,
            (__attribute__((address_space(3))) void*)&MsT[jj * 512], 16, 0, 0);
    }

    // ---- Q fragments for this wave's 32-query slice (fp16), q on l16 ----
    h8v qf[2][4];
    #pragma unroll
    for (int qt = 0; qt < 2; ++qt) {
        const float* qp = query + (size_t)(q0 + wv * 32 + qt * 16 + l16) * DIM + quad * 8;
        #pragma unroll
        for (int ks = 0; ks < 4; ++ks) {
            const float4 a = *(const float4*)(qp + ks * 32);
            const float4 b = *(const float4*)(qp + ks * 32 + 4);
            h8v vh;
            vh[0] = (_Float16)a.x; vh[1] = (_Float16)a.y;
            vh[2] = (_Float16)a.z; vh[3] = (_Float16)a.w;
            vh[4] = (_Float16)b.x; vh[5] = (_Float16)b.y;
            vh[6] = (_Float16)b.z; vh[7] = (_Float16)b.w;
            qf[qt][ks] = vh;
        }
    }

    f4v oacc[8][2];                            // PV acc: 8 q-tiles x 2 d-tiles (R10)
    float dacc[2] = {0.f, 0.f};                // den partials: per qt, q = l16
    #pragma unroll
    for (int qt = 0; qt < 8; ++qt) {
        oacc[qt][0] = (f4v){0.f, 0.f, 0.f, 0.f};
        oacc[qt][1] = (f4v){0.f, 0.f, 0.f, 0.f};
    }

    for (int it = 0; it < ITERS; ++it) {
        // next tile base (last iter: clamp -> harmless in-bounds refetch,
        // drained by the post-loop __syncthreads before SM reuse)
        const int nnx = nbase + ((it + 1 == ITERS) ? 0 : (it + 1) * TN);

        // F[it] landed (own 4 oldest); T[it] (4) stays in flight. lgkmcnt(0)
        // drains this wave's prev-iter PV ds_reads (cross-wave Ps!) before the
        // rendezvous, so post-barrier Ps writes can't corrupt them.
        asm volatile("s_waitcnt vmcnt(4) lgkmcnt(0)" ::: "memory");
        __builtin_amdgcn_s_barrier();
        __builtin_amdgcn_sched_barrier(0);

        // ---- QK^T swapped: sacc = mfma(Mrow-frag, Q-frag) = S^T ----
        f4v sacc[2][4];
        #pragma unroll
        for (int qt = 0; qt < 2; ++qt)
            #pragma unroll
            for (int nt = 0; nt < 4; ++nt)
                sacc[qt][nt] = (f4v){0.f, 0.f, 0.f, 0.f};
        #pragma unroll
        for (int nt = 0; nt < 4; ++nt) {
            const int r   = nt * 16 + l16;     // A-row = mem row (lane l16)
            const int rsw = r & 7;
            #pragma unroll
            for (int ks = 0; ks < 4; ++ks) {
                const int c = ks * 4 + quad;
                const h8v bm = *(const h8v*)&MsF16[r * DIM + ((c ^ rsw) << 3)];
                #pragma unroll
                for (int qt = 0; qt < 2; ++qt)
                    sacc[qt][nt] = __builtin_amdgcn_mfma_f32_16x16x32_f16(bm, qf[qt][ks], sacc[qt][nt], 0, 0, 0);
            }
        }

        // ---- exp + P^T write: 4 consecutive n per lane -> one b64 ----
        #pragma unroll
        for (int qt = 0; qt < 2; ++qt) {
            const int qloc = wv * 32 + qt * 16 + l16;
            #pragma unroll
            for (int nt = 0; nt < 4; ++nt) {
                const uint16_t pb0 = f2bf(__expf(sacc[qt][nt][0] - SHIFT));
                const uint16_t pb1 = f2bf(__expf(sacc[qt][nt][1] - SHIFT));
                const uint16_t pb2 = f2bf(__expf(sacc[qt][nt][2] - SHIFT));
                const uint16_t pb3 = f2bf(__expf(sacc[qt][nt][3] - SHIFT));
                dacc[qt] += (bf2f(pb0) + bf2f(pb1)) + (bf2f(pb2) + bf2f(pb3));
                uint2 w;
                w.x = (uint32_t)pb0 | ((uint32_t)pb1 << 16);
                w.y = (uint32_t)pb2 | ((uint32_t)pb3 << 16);
                // Ps[q][n = nt*16 + quad*4 + {0..3}] = P[n][q]
                *(uint2*)&Ps[qloc * PSTR + nt * 16 + quad * 4] = w;
            }
        }

        // Ps^T visible to all waves; all QK reads of MsF16[it] completed ->
        // safe to overwrite with F[it+1].
        asm volatile("s_waitcnt lgkmcnt(0)" ::: "memory");
        __builtin_amdgcn_s_barrier();
        __builtin_amdgcn_sched_barrier(0);

        // ---- issue F[it+1] (hides under PV) ----
        #pragma unroll
        for (int ii = 0; ii < 4; ++ii) {
            const int fid = wv * 4 + ii;
            const int s = fid * 64 + lane;
            const int r = s >> 4, c = (s & 15) ^ (r & 7);
            const uint16_t* g = mf16 + (size_t)(nnx + r) * DIM + c * 8;
            __builtin_amdgcn_global_load_lds(
                (const __attribute__((address_space(1))) void*)g,
                (__attribute__((address_space(3))) void*)&MsF16[fid * 512], 16, 0, 0);
        }

        // T[it] landed (own 4 oldest; exactly the d-rows this wave reads below).
        asm volatile("s_waitcnt vmcnt(4)" ::: "memory");

        // ---- PV (R10 verbatim): wave wv owns d in [wv*32, wv*32+32) ----
        #pragma unroll
        for (int ksP = 0; ksP < 2; ++ksP) {
            s8v bt[2];
            #pragma unroll
            for (int dt = 0; dt < 2; ++dt) {
                const int d  = wv * 32 + dt * 16 + l16;
                const int cg = ksP * 4 + quad;
                bt[dt] = *(const s8v*)&MsT[d * TN + ((cg ^ (d & 7)) << 3)];
            }
            #pragma unroll
            for (int qt = 0; qt < 8; ++qt) {
                const int q = qt * 16 + l16;
                const s8v pf = *(const s8v*)&Ps[q * PSTR + ksP * 32 + quad * 8];
                oacc[qt][0] = __builtin_amdgcn_mfma_f32_16x16x32_bf16(pf, bt[0], oacc[qt][0], 0, 0, 0);
                oacc[qt][1] = __builtin_amdgcn_mfma_f32_16x16x32_bf16(pf, bt[1], oacc[qt][1], 0, 0, 0);
            }
        }

        // Own PV ds_reads complete before their MsT rows are DMA-overwritten.
        asm volatile("s_waitcnt lgkmcnt(0)" ::: "memory");

        // ---- issue T[it+1]: overwrites only rows this wave already consumed --
        #pragma unroll
        for (int ii = 0; ii < 4; ++ii) {
            const int jj = wv * 4 + ii;
            const int s = jj * 64 + lane;
            const int d = s >> 3, c = (s & 7) ^ (d & 7);
            const uint16_t* g = mhit + (size_t)d * NMEM + nnx + c * 8;
            __builtin_amdgcn_global_load_lds(
                (const __attribute__((address_space(1))) void*)g,
                (__attribute__((address_space(3))) void*)&MsT[jj * 512], 16, 0, 0);
        }
    }

    // ---- denominator: q = l16; sum the 4 quads' disjoint n-sets ----
    #pragma unroll
    for (int qt = 0; qt < 2; ++qt) {
        dacc[qt] += __shfl_xor(dacc[qt], 16, 64);
        dacc[qt] += __shfl_xor(dacc[qt], 32, 64);
    }
    __syncthreads();                           // full drain (incl. tail DMA); SM reusable
    if (quad == 0) {
        #pragma unroll
        for (int qt = 0; qt < 2; ++qt)
            den[chunk * NQ_TOT + q0 + wv * 32 + qt * 16 + l16] = dacc[qt];
    }
    // ---- O merge into LDS (bf16) for coalesced stores (R10 verbatim) ----
    uint16_t* Obuf = SM;                       // 128 q x 128 d x 2B = 32 KB
    #pragma unroll
    for (int qt = 0; qt < 8; ++qt)
        #pragma unroll
        for (int dt = 0; dt < 2; ++dt)
            #pragma unroll
            for (int rg = 0; rg < 4; ++rg) {
                const int qq = qt * 16 + quad * 4 + rg;
                const int dd = wv * 32 + dt * 16 + l16;
                Obuf[qq * DIM + dd] = f2bf(oacc[qt][dt][rg]);
            }
    __syncthreads();
    {
        uint4* dst = (uint4*)(num + ((size_t)chunk * NQ_TOT + q0) * DIM);
        const uint4* src = (const uint4*)Obuf;
        #pragma unroll
        for (int k = 0; k < 8; ++k) {
            const int f = tid + k * 256;       // 2048 uint4s (32 KB)
            dst[f] = src[f];
        }
    }
}

// ============ final reduce over chunks + normalize ============
template <int NCHK>
__global__ __launch_bounds__(256)
void reduce_kernel(const uint16_t* __restrict__ num, const float* __restrict__ den,
                   float* __restrict__ out) {
    const int f = blockIdx.x * 256 + threadIdx.x;   // 65536 groups of 4
    const int q = f >> 5;
    float4 ns = make_float4(0.f, 0.f, 0.f, 0.f);
    float ds = 0.f;
    #pragma unroll
    for (int c = 0; c < NCHK; ++c) {
        const ushort4 v = ((const ushort4*)num)[c * (NQ_TOT * DIM / 4) + f];
        ns.x += bf2f(v.x); ns.y += bf2f(v.y); ns.z += bf2f(v.z); ns.w += bf2f(v.w);
        ds += den[c * NQ_TOT + q];
    }
    const float inv = 1.0f / ds;
    ((float4*)out)[f] = make_float4(ns.x * inv, ns.y * inv, ns.z * inv, ns.w * inv);
}

// ============ fallback (round-1 fp32 kernel) if ws too small ============
#define FTQ 8
#define FTN 64
#define FNTILES (NMEM / FTN)
#define FBLOCK 512
#define MPAD 132
#define PPAD 68

__global__ __launch_bounds__(FBLOCK, 2)
void sparse_attn_fp32(const float* __restrict__ query,
                      const float* __restrict__ memory,
                      float* __restrict__ out) {
    __shared__ float Qs[FTQ * MPAD];
    __shared__ float Ms[FTN * MPAD];
    __shared__ float Psh[FTQ * PPAD];
    __shared__ float Rd[FTQ * PPAD];
    const int tid = threadIdx.x;
    const int q = tid & 7, rest = tid >> 3;
    const int ng = rest, dg = rest & 31, half = rest >> 5;
    const long q0 = (long)blockIdx.x * FTQ;
    if (tid < FTQ * DIM / 4) {
        const float4 v = ((const float4*)(query + q0 * DIM))[tid];
        *(float4*)&Qs[(tid >> 5) * MPAD + ((tid & 31) << 2)] = v;
    }
    float4 pf[4];
    {
        const float4* msrc = (const float4*)memory;
        #pragma unroll
        for (int k = 0; k < 4; ++k) pf[k] = msrc[tid + k * FBLOCK];
    }
    float4 acc = make_float4(0.f, 0.f, 0.f, 0.f);
    float l_part = 0.f;
    for (int t = 0; t < FNTILES; ++t) {
        __syncthreads();
        #pragma unroll
        for (int k = 0; k < 4; ++k) {
            const int f4 = tid + k * FBLOCK;
            *(float4*)&Ms[(f4 >> 5) * MPAD + ((f4 & 31) << 2)] = pf[k];
        }
        __syncthreads();
        if (t + 1 < FNTILES) {
            const float4* msrc = (const float4*)(memory + (long)(t + 1) * FTN * DIM);
            #pragma unroll
            for (int k = 0; k < 4; ++k) pf[k] = msrc[tid + k * FBLOCK];
        }
        float4 s4 = make_float4(0.f, 0.f, 0.f, 0.f);
        const float* qrow = &Qs[q * MPAD];
        const float* mrow = &Ms[ng * MPAD];
        #pragma unroll
        for (int jj = 0; jj < 32; ++jj) {
            const float4 qv = *(const float4*)&qrow[jj * 4];
            const float4 mv = *(const float4*)&mrow[jj * 4];
            s4.x += qv.x * mv.x; s4.y += qv.y * mv.y;
            s4.z += qv.z * mv.z; s4.w += qv.w * mv.w;
        }
        const float p = __expf(((s4.x + s4.y) + (s4.z + s4.w)) - SHIFT);
        Psh[q * PPAD + ng] = p;
        l_part += p;
        __syncthreads();
        #pragma unroll
        for (int n = 0; n < 32; ++n) {
            const int nn = half * 32 + n;
            const float pw = Psh[q * PPAD + nn];
            const float4 mv = *(const float4*)&Ms[nn * MPAD + dg * 4];
            acc.x += pw * mv.x; acc.y += pw * mv.y;
            acc.z += pw * mv.z; acc.w += pw * mv.w;
        }
    }
    __syncthreads();
    Rd[q * PPAD + rest] = l_part;
    if (half == 1) *(float4*)&Ms[q * MPAD + dg * 4] = acc;
    __syncthreads();
    if (half == 0) {
        const float4 o2 = *(const float4*)&Ms[q * MPAD + dg * 4];
        float l = 0.f;
        #pragma unroll 8
        for (int i = 0; i < 64; ++i) l += Rd[q * PPAD + i];
        const float inv = 1.0f / l;
        float4 o;
        o.x = (acc.x + o2.x) * inv; o.y = (acc.y + o2.y) * inv;
        o.z = (acc.z + o2.z) * inv; o.w = (acc.w + o2.w) * inv;
        *(float4*)(out + (q0 + q) * DIM + dg * 4) = o;
    }
}

extern "C" void kernel_launch(void* const* d_in, const int* in_sizes, int n_in,
                              void* d_out, int out_size, void* d_ws, size_t ws_size,
                              hipStream_t stream) {
    const float* query  = (const float*)d_in[0];
    const float* memory = (const float*)d_in[1];
    float* out = (float*)d_out;
    if (ws_size >= WS_NEED(16)) {
        uint16_t* mf16 = (uint16_t*)((char*)d_ws + OFF_MF16);
        uint16_t* mhit = (uint16_t*)((char*)d_ws + OFF_MHIT);
        uint16_t* num  = (uint16_t*)((char*)d_ws + OFF_NUM);
        convert_kernel<<<NMEM / 64, 256, 0, stream>>>(memory, mf16, mhit);
        if (ws_size >= WS_NEED(32)) {
            float* den = (float*)((char*)d_ws + OFF_DEN(32));
            attn_kernel<32><<<QROWS * 32, 256, 0, stream>>>(query, mf16, mhit, num, den);
            reduce_kernel<32><<<NQ_TOT * DIM / 4 / 256, 256, 0, stream>>>(num, den, out);
        } else {
            float* den = (float*)((char*)d_ws + OFF_DEN(16));
            attn_kernel<16><<<QROWS * 16, 256, 0, stream>>>(query, mf16, mhit, num, den);
            reduce_kernel<16><<<NQ_TOT * DIM / 4 / 256, 256, 0, stream>>>(num, den, out);
        }
    } else {
        sparse_attn_fp32<<<NQ_TOT / FTQ, FBLOCK, 0, stream>>>(query, memory, out);
    }
}